// Round 5
// baseline (115.330 us; speedup 1.0000x reference)
//
#include <hip/hip_runtime.h>
#include <math.h>

#define NN 4096
#define CC 64
#define CAP 256                 // member capacity per cluster (mean 64, sd ~8 -> huge margin)
#define QS 8                    // pair-space slices per cluster
#define K3_THREADS 128

constexpr float K_MARGIN = 0.4f;
constexpr float K_GAMMA  = 80.0f;
// logit_p = -max(1.4 - s, 0)*(s - 0.6)*80 with s = tanh(.) in (-1,1)  =>  logit_p in (-12.8, 307.2)
constexpr float M_P = 307.2f;

// Exact identities used (verified passing with absmax 0.0 in rounds 1/4):
//   prob==0 on all different-cluster pairs  => wn_mean == 0.0f exactly => negative LSE term vanishes.
//   4096 rows into 64 clusters (pigeonhole) => >=1 positive pair => wp_mean == 1.
//   loss = softplus( logsumexp_{i<j, same cluster} logit_p(sim[i,j]) )
//
// ws layout: int cnt[64] @ 0 (256 B); uint16 members[64][256] @ 256 (32 KB);
//            float partials[512] @ 33024 (16B-aligned).

__global__ void zero_kernel(int* __restrict__ cnt) {
    if (threadIdx.x < CC) cnt[threadIdx.x] = 0;   // ws is poisoned 0xAA each launch
}

__global__ __launch_bounds__(256) void ids_bucket_kernel(const float* __restrict__ clusters,
                                                         int* __restrict__ cnt,
                                                         unsigned short* __restrict__ members) {
    const int row  = (blockIdx.x * 256 + threadIdx.x) >> 6;  // one wave per row
    const int lane = threadIdx.x & 63;
    const float v = clusters[row * CC + lane];               // CC==64: coalesced, exact one-hot
    const unsigned long long m = __ballot(v > 0.5f);
    if (lane == 0) {
        const int id   = (int)__builtin_ctzll(m);
        const int slot = atomicAdd(&cnt[id], 1);             // order irrelevant (min/max below)
        members[id * CAP + slot] = (unsigned short)row;
    }
}

__global__ __launch_bounds__(K3_THREADS) void pairs_kernel(const float* __restrict__ sim,
                                                           const int* __restrict__ cnt,
                                                           const unsigned short* __restrict__ members,
                                                           float* __restrict__ partials) {
    const int c = blockIdx.x >> 3;     // cluster
    const int q = blockIdx.x & (QS - 1);
    __shared__ int M[CAP];
    const int m = cnt[c];
    for (int t = threadIdx.x; t < m; t += K3_THREADS) M[t] = members[c * CAP + t];
    __syncthreads();

    float s_p = 0.f;
    for (int t = threadIdx.x; t < m; t += K3_THREADS) {
        const int r1 = M[t];
        for (int a = q; a < t; a += QS) {                    // slices q=0..7 tile a in [0,t) exactly once
            const int r0 = M[a];                              // wave-uniform-ish LDS broadcast
            const int i2 = min(r0, r1);
            const int j2 = r0 ^ r1 ^ i2;                      // max
            const float s = sim[i2 * NN + j2];                // i2*NN+j2 < 2^24, upper triangle
            const float lp = -fmaxf(1.0f + K_MARGIN - s, 0.0f) * (s - (1.0f - K_MARGIN)) * K_GAMMA;
            s_p += __expf(lp - M_P);
        }
    }

    // 64-lane butterfly, then combine the block's 2 waves
    #pragma unroll
    for (int off = 32; off > 0; off >>= 1) s_p += __shfl_xor(s_p, off);
    __shared__ float red[2];
    const int wave = threadIdx.x >> 6;
    if ((threadIdx.x & 63) == 0) red[wave] = s_p;
    __syncthreads();
    if (threadIdx.x == 0) partials[blockIdx.x] = red[0] + red[1];
}

__device__ inline float softplus_f(float x) {
    return fmaxf(x, 0.0f) + log1pf(expf(-fabsf(x)));  // maps -inf -> 0
}

__global__ __launch_bounds__(256) void final_kernel(const float* __restrict__ partials,
                                                    float* __restrict__ out) {
    float s = partials[threadIdx.x] + partials[threadIdx.x + 256];   // 512 partials
    #pragma unroll
    for (int off = 32; off > 0; off >>= 1) s += __shfl_xor(s, off);
    __shared__ float red[4];
    const int wave = threadIdx.x >> 6;
    if ((threadIdx.x & 63) == 0) red[wave] = s;
    __syncthreads();
    if (threadIdx.x == 0) {
        const float S = red[0] + red[1] + red[2] + red[3];
        out[0] = softplus_f(logf(S) + M_P);   // wp_mean==1, wn term ==0 exactly
    }
}

extern "C" void kernel_launch(void* const* d_in, const int* in_sizes, int n_in,
                              void* d_out, int out_size, void* d_ws, size_t ws_size,
                              hipStream_t stream) {
    const float* sim      = (const float*)d_in[0];
    const float* clusters = (const float*)d_in[1];
    float* out = (float*)d_out;

    int*            cnt      = (int*)d_ws;
    unsigned short* members  = (unsigned short*)((char*)d_ws + 256);
    float*          partials = (float*)((char*)d_ws + 33024);

    zero_kernel<<<1, 64, 0, stream>>>(cnt);
    ids_bucket_kernel<<<(NN * 64) / 256, 256, 0, stream>>>(clusters, cnt, members); // 1024 blocks
    pairs_kernel<<<CC * QS, K3_THREADS, 0, stream>>>(sim, cnt, members, partials);  // 512 blocks
    final_kernel<<<1, 256, 0, stream>>>(partials, out);
}

// Round 7
// 99.780 us; speedup vs baseline: 1.1558x; 1.1558x over previous
//
#include <hip/hip_runtime.h>
#include <math.h>

#define NN 4096
#define CC 64
#define MAXM 512               // max cluster size we support (actual ~64±8, huge margin)
#define QS 8                   // pair-space slices per cluster
#define K3_THREADS 128

constexpr float K_MARGIN = 0.4f;
constexpr float K_GAMMA  = 80.0f;
// logit_p = -max(1.4 - s, 0)*(s - 0.6)*80 with s = tanh(.) in (-1,1)  =>  logit_p in (-12.8, 307.2)
constexpr float M_P = 307.2f;

// Exact identities (verified absmax 0.0 in rounds 1/4/5):
//   prob==0 on different-cluster pairs => wn_mean == 0.0f exactly => negative term vanishes.
//   4096 rows into 64 clusters => >=1 positive pair => wp_mean == 1.
//   loss = softplus( logsumexp_{i<j, same cluster} logit_p(sim[i,j]) )
//
// ws layout: int ids[4096] @ 0 (16 KB); u16 members[4096] @ 16384 (8 KB);
//            int cntG[64] @ 24576; int offG[64] @ 24832; float partials[512] @ 25088.

__global__ __launch_bounds__(256) void ids_kernel(const float* __restrict__ clusters,
                                                  int* __restrict__ ids) {
    const int row  = (blockIdx.x * 256 + threadIdx.x) >> 6;  // one wave per row
    const int lane = threadIdx.x & 63;
    const float v = clusters[row * CC + lane];               // CC==64: coalesced, exact one-hot
    const unsigned long long m = __ballot(v > 0.5f);
    if (lane == 0) ids[row] = (int)__builtin_ctzll(m);
}

// Single block: counting sort of 4096 rows into 64 compact cluster lists. No global atomics.
__global__ __launch_bounds__(1024) void bucket_kernel(const int* __restrict__ ids,
                                                      unsigned short* __restrict__ members,
                                                      int* __restrict__ cntG,
                                                      int* __restrict__ offG) {
    __shared__ int cnt[CC];
    __shared__ int off[CC];
    __shared__ int place[CC];
    const int t = threadIdx.x;
    if (t < CC) cnt[t] = 0;
    __syncthreads();

    const int4 my = reinterpret_cast<const int4*>(ids)[t];   // rows 4t..4t+3
    atomicAdd(&cnt[my.x], 1);
    atomicAdd(&cnt[my.y], 1);
    atomicAdd(&cnt[my.z], 1);
    atomicAdd(&cnt[my.w], 1);
    __syncthreads();

    if (t == 0) {                                            // exclusive scan over 64 counters
        int run = 0;
        for (int c = 0; c < CC; ++c) { off[c] = run; place[c] = run; run += cnt[c]; }
    }
    __syncthreads();

    const int r0 = 4 * t;
    int p;
    p = atomicAdd(&place[my.x], 1); members[p] = (unsigned short)(r0 + 0);
    p = atomicAdd(&place[my.y], 1); members[p] = (unsigned short)(r0 + 1);
    p = atomicAdd(&place[my.z], 1); members[p] = (unsigned short)(r0 + 2);
    p = atomicAdd(&place[my.w], 1); members[p] = (unsigned short)(r0 + 3);

    if (t < CC) { cntG[t] = cnt[t]; offG[t] = off[t]; }
}

__global__ __launch_bounds__(K3_THREADS) void pairs_kernel(const float* __restrict__ sim,
                                                           const int* __restrict__ cntG,
                                                           const int* __restrict__ offG,
                                                           const unsigned short* __restrict__ members,
                                                           float* __restrict__ partials) {
    const int c = blockIdx.x >> 3;     // cluster
    const int q = blockIdx.x & (QS - 1);
    __shared__ int M[MAXM];
    const int m    = cntG[c];
    const int base = offG[c];
    for (int t = threadIdx.x; t < m && t < MAXM; t += K3_THREADS) M[t] = members[base + t];
    __syncthreads();

    float s_p = 0.f;
    for (int t = threadIdx.x; t < m; t += K3_THREADS) {
        const int r1 = M[t];
        for (int a = q; a < t; a += QS) {                    // slices q=0..7 tile a in [0,t) exactly once
            const int r0 = M[a];                              // broadcast LDS read (uniform per iter)
            const int i2 = min(r0, r1);
            const int j2 = r0 ^ r1 ^ i2;                      // max
            const float s = sim[i2 * NN + j2];                // upper triangle gather
            const float lp = -fmaxf(1.0f + K_MARGIN - s, 0.0f) * (s - (1.0f - K_MARGIN)) * K_GAMMA;
            s_p += __expf(lp - M_P);
        }
    }

    #pragma unroll
    for (int off = 32; off > 0; off >>= 1) s_p += __shfl_xor(s_p, off);
    __shared__ float red[2];
    if ((threadIdx.x & 63) == 0) red[threadIdx.x >> 6] = s_p;
    __syncthreads();
    if (threadIdx.x == 0) partials[blockIdx.x] = red[0] + red[1];
}

__device__ inline float softplus_f(float x) {
    return fmaxf(x, 0.0f) + log1pf(expf(-fabsf(x)));  // maps -inf -> 0
}

__global__ __launch_bounds__(256) void final_kernel(const float* __restrict__ partials,
                                                    float* __restrict__ out) {
    float s = partials[threadIdx.x] + partials[threadIdx.x + 256];   // 512 partials
    #pragma unroll
    for (int off = 32; off > 0; off >>= 1) s += __shfl_xor(s, off);
    __shared__ float red[4];
    if ((threadIdx.x & 63) == 0) red[threadIdx.x >> 6] = s;
    __syncthreads();
    if (threadIdx.x == 0) {
        const float S = red[0] + red[1] + red[2] + red[3];
        out[0] = softplus_f(logf(S) + M_P);   // wp_mean==1, wn term ==0 exactly
    }
}

extern "C" void kernel_launch(void* const* d_in, const int* in_sizes, int n_in,
                              void* d_out, int out_size, void* d_ws, size_t ws_size,
                              hipStream_t stream) {
    const float* sim      = (const float*)d_in[0];
    const float* clusters = (const float*)d_in[1];
    float* out = (float*)d_out;

    int*            ids      = (int*)d_ws;
    unsigned short* members  = (unsigned short*)((char*)d_ws + 16384);
    int*            cntG     = (int*)((char*)d_ws + 24576);
    int*            offG     = (int*)((char*)d_ws + 24832);
    float*          partials = (float*)((char*)d_ws + 25088);

    ids_kernel<<<(NN * 64) / 256, 256, 0, stream>>>(clusters, ids);                    // 1024 blocks
    bucket_kernel<<<1, 1024, 0, stream>>>(ids, members, cntG, offG);                   // 1 block
    pairs_kernel<<<CC * QS, K3_THREADS, 0, stream>>>(sim, cntG, offG, members, partials); // 512 blocks
    final_kernel<<<1, 256, 0, stream>>>(partials, out);
}

// Round 8
// 99.025 us; speedup vs baseline: 1.1647x; 1.0076x over previous
//
#include <hip/hip_runtime.h>
#include <math.h>

#define NN 4096
#define CC 64

constexpr float K_MARGIN = 0.4f;
constexpr float K_GAMMA  = 80.0f;
// logit_p = -max(1.4 - s, 0)*(s - 0.6)*80 with s = tanh(.) in (-1,1)  =>  logit_p in (-12.8, 307.2)
constexpr float M_P = 307.2f;

// Exact identities (verified absmax 0.0 in rounds 1/4/5/7):
//   prob==0 on different-cluster pairs => wn_mean == 0.0f exactly => negative term vanishes.
//   4096 rows into 64 clusters (pigeonhole) => >=1 positive pair => wp_mean == 1.
//   loss = softplus( logsumexp_{i<j, same cluster} logit_p(sim[i,j]) )
//
// ws layout: int ids[4096] @ 0 (16 KB); float partials[2048] @ 16384 (8 KB).

__global__ __launch_bounds__(256) void ids_kernel(const float* __restrict__ clusters,
                                                  int* __restrict__ ids) {
    const int row  = (blockIdx.x * 256 + threadIdx.x) >> 6;  // one wave per row
    const int lane = threadIdx.x & 63;
    const float v = clusters[row * CC + lane];               // CC==64: coalesced, exact one-hot
    const unsigned long long m = __ballot(v > 0.5f);
    if (lane == 0) ids[row] = (int)__builtin_ctzll(m);
}

// Block b owns rows b and 4095-b (4095 j-comparisons total -> perfectly balanced).
// ids live in LDS; sim is gathered ONLY on id-match (~1/64 of pairs), staying
// within the row's contiguous 16 KB -> good line locality. No sort, no atomics.
__global__ __launch_bounds__(256) void pairs_row_kernel(const float* __restrict__ sim,
                                                        const int* __restrict__ ids,
                                                        float* __restrict__ partials) {
    __shared__ int ids_s[NN];
    for (int t = threadIdx.x; t < NN / 4; t += 256)
        reinterpret_cast<int4*>(ids_s)[t] = reinterpret_cast<const int4*>(ids)[t];
    __syncthreads();

    float s_p = 0.f;
    #pragma unroll
    for (int r = 0; r < 2; ++r) {
        const int i   = (r == 0) ? (int)blockIdx.x : (NN - 1 - (int)blockIdx.x);
        const int idi = ids_s[i];
        const float* row = sim + (size_t)i * NN;
        for (int j = i + 1 + (int)threadIdx.x; j < NN; j += 256) {
            if (ids_s[j] == idi) {                           // ~64 matches per row
                const float s  = row[j];
                const float lp = -fmaxf(1.0f + K_MARGIN - s, 0.0f) * (s - (1.0f - K_MARGIN)) * K_GAMMA;
                s_p += __expf(lp - M_P);
            }
        }
    }

    #pragma unroll
    for (int off = 32; off > 0; off >>= 1) s_p += __shfl_xor(s_p, off);
    __shared__ float red[4];
    if ((threadIdx.x & 63) == 0) red[threadIdx.x >> 6] = s_p;
    __syncthreads();
    if (threadIdx.x == 0) partials[blockIdx.x] = red[0] + red[1] + red[2] + red[3];
}

__device__ inline float softplus_f(float x) {
    return fmaxf(x, 0.0f) + log1pf(expf(-fabsf(x)));  // maps -inf -> 0
}

__global__ __launch_bounds__(256) void final_kernel(const float* __restrict__ partials,
                                                    float* __restrict__ out) {
    float s = 0.f;
    #pragma unroll
    for (int k = 0; k < 2; ++k) {                            // 2048 floats as 2x float4/thread
        const float4 p = reinterpret_cast<const float4*>(partials)[threadIdx.x + k * 256];
        s += p.x + p.y + p.z + p.w;
    }
    #pragma unroll
    for (int off = 32; off > 0; off >>= 1) s += __shfl_xor(s, off);
    __shared__ float red[4];
    if ((threadIdx.x & 63) == 0) red[threadIdx.x >> 6] = s;
    __syncthreads();
    if (threadIdx.x == 0) {
        const float S = red[0] + red[1] + red[2] + red[3];
        out[0] = softplus_f(logf(S) + M_P);   // wp_mean==1, wn term ==0 exactly
    }
}

extern "C" void kernel_launch(void* const* d_in, const int* in_sizes, int n_in,
                              void* d_out, int out_size, void* d_ws, size_t ws_size,
                              hipStream_t stream) {
    const float* sim      = (const float*)d_in[0];
    const float* clusters = (const float*)d_in[1];
    float* out = (float*)d_out;

    int*   ids      = (int*)d_ws;
    float* partials = (float*)((char*)d_ws + 16384);

    ids_kernel<<<(NN * 64) / 256, 256, 0, stream>>>(clusters, ids);            // 1024 blocks
    pairs_row_kernel<<<NN / 2, 256, 0, stream>>>(sim, ids, partials);          // 2048 blocks
    final_kernel<<<1, 256, 0, stream>>>(partials, out);
}